// Round 1
// baseline (564.135 us; speedup 1.0000x reference)
//
#include <hip/hip_runtime.h>

// Fused ragged gather + segment-mean.
// Inputs (setup_inputs order):
//   d_in[0] char_ids      int32 [8e6]
//   d_in[1] segment_ids   int32 [8e6] (SORTED ascending)
//   d_in[2] num_words     int32 [1]   (device scalar; host uses out_size/E instead)
//   d_in[3] embedding_tab f32   [256*50]
// Output: f32 [num_words, 50]

#define EMB 50
#define EMB2 25  // float2 per row

// K1: starts[w] = lower_bound(segment_ids, w), for w in [0, num_words].
// Thread i covers words (seg[i-1], seg[i]] -> every entry written exactly once,
// including runs for empty words and the sentinel starts[num_words] = n.
__global__ __launch_bounds__(256) void seg_starts_kernel(
    const int* __restrict__ seg, int* __restrict__ starts, int n, int num_words) {
  int i = blockIdx.x * blockDim.x + threadIdx.x;
  if (i > n) return;
  int cur  = (i < n) ? seg[i]     : num_words;
  int prev = (i > 0) ? seg[i - 1] : -1;
  for (int w = prev + 1; w <= cur; ++w) starts[w] = i;
}

// K2: one thread per word. Gather rows from the (L1/L2-hot) table, mean, store.
__global__ __launch_bounds__(256) void word_mean_kernel(
    const int* __restrict__ char_ids, const float* __restrict__ table,
    const int* __restrict__ starts, float* __restrict__ out, int num_words) {
  int w = blockIdx.x * blockDim.x + threadIdx.x;
  if (w >= num_words) return;
  int s = starts[w];
  int e = starts[w + 1];

  float ax[EMB2], ay[EMB2];
#pragma unroll
  for (int k = 0; k < EMB2; ++k) { ax[k] = 0.f; ay[k] = 0.f; }

  for (int i = s; i < e; ++i) {
    int c = char_ids[i];
    const float2* row = (const float2*)(table + c * EMB);  // 200B rows, 8B aligned
#pragma unroll
    for (int k = 0; k < EMB2; ++k) {
      float2 v = row[k];
      ax[k] += v.x;
      ay[k] += v.y;
    }
  }

  int cnt = e - s;
  float inv = (cnt > 0) ? (1.0f / (float)cnt) : 0.0f;  // empty word -> zeros (== sum0/max(cnt,1))
  float2* orow = (float2*)(out + (size_t)w * EMB);
#pragma unroll
  for (int k = 0; k < EMB2; ++k) {
    orow[k] = make_float2(ax[k] * inv, ay[k] * inv);
  }
}

// Fallback if d_ws can't hold starts[]: per-thread binary search (2x lower_bound).
__device__ __forceinline__ int lb(const int* __restrict__ seg, int n, int w) {
  int lo = 0, hi = n;
  while (lo < hi) {
    int mid = (lo + hi) >> 1;
    if (seg[mid] < w) lo = mid + 1; else hi = mid;
  }
  return lo;
}

__global__ __launch_bounds__(256) void word_mean_bs_kernel(
    const int* __restrict__ char_ids, const int* __restrict__ seg,
    const float* __restrict__ table, float* __restrict__ out, int n, int num_words) {
  int w = blockIdx.x * blockDim.x + threadIdx.x;
  if (w >= num_words) return;
  int s = lb(seg, n, w);
  int e = lb(seg, n, w + 1);

  float ax[EMB2], ay[EMB2];
#pragma unroll
  for (int k = 0; k < EMB2; ++k) { ax[k] = 0.f; ay[k] = 0.f; }

  for (int i = s; i < e; ++i) {
    int c = char_ids[i];
    const float2* row = (const float2*)(table + c * EMB);
#pragma unroll
    for (int k = 0; k < EMB2; ++k) {
      float2 v = row[k];
      ax[k] += v.x;
      ay[k] += v.y;
    }
  }

  int cnt = e - s;
  float inv = (cnt > 0) ? (1.0f / (float)cnt) : 0.0f;
  float2* orow = (float2*)(out + (size_t)w * EMB);
#pragma unroll
  for (int k = 0; k < EMB2; ++k) {
    orow[k] = make_float2(ax[k] * inv, ay[k] * inv);
  }
}

extern "C" void kernel_launch(void* const* d_in, const int* in_sizes, int n_in,
                              void* d_out, int out_size, void* d_ws, size_t ws_size,
                              hipStream_t stream) {
  const int*   char_ids = (const int*)d_in[0];
  const int*   seg      = (const int*)d_in[1];
  const float* table    = (const float*)d_in[3];
  float*       out      = (float*)d_out;

  const int n  = in_sizes[0];        // total chars (8,000,000)
  const int nw = out_size / EMB;     // num_words (1,600,000); device scalar unreadable in capture

  if (ws_size >= (size_t)(nw + 1) * sizeof(int)) {
    int* starts = (int*)d_ws;
    // n+1 threads: covers i == n sentinel.
    seg_starts_kernel<<<(n + 256) / 256, 256, 0, stream>>>(seg, starts, n, nw);
    word_mean_kernel<<<(nw + 255) / 256, 256, 0, stream>>>(char_ids, table, starts, out, nw);
  } else {
    word_mean_bs_kernel<<<(nw + 255) / 256, 256, 0, stream>>>(char_ids, seg, table, out, n, nw);
  }
}

// Round 2
// 546.903 us; speedup vs baseline: 1.0315x; 1.0315x over previous
//
#include <hip/hip_runtime.h>

// Fused ragged gather + segment-mean (sorted segment_ids).
// d_in[0] char_ids i32[8e6], d_in[1] segment_ids i32[8e6] sorted,
// d_in[2] num_words i32[1] (unused on host; out_size/50 instead),
// d_in[3] embedding_table f32[256*50]. Out: f32[num_words,50].

#define NB 256
#define EMB 50
#define PAIRS 25          // float2 per embedding row
#define BLK 1024          // 2 blocks/CU with 50KB LDS -> 100% occupancy cap

// ---------------- K1: starts[w] = lower_bound(seg, w), w in [0, nw] ----------
// 4 chars per thread via int4; sentinel run written by the tail-owning thread.
__global__ __launch_bounds__(256) void seg_starts4(
    const int* __restrict__ seg, int* __restrict__ starts, int n, int nw) {
  int base = (blockIdx.x * blockDim.x + threadIdx.x) * 4;
  if (base >= n) return;
  int lim = n - base; if (lim > 4) lim = 4;
  int vals[4];
  if (lim == 4) {
    int4 v = *(const int4*)(seg + base);
    vals[0] = v.x; vals[1] = v.y; vals[2] = v.z; vals[3] = v.w;
  } else {
    for (int u = 0; u < lim; ++u) vals[u] = seg[base + u];
  }
  int prev = (base > 0) ? seg[base - 1] : -1;
  for (int u = 0; u < lim; ++u) {
    int cur = vals[u];
    for (int w = prev + 1; w <= cur; ++w) starts[w] = base + u;
    prev = cur;
  }
  if (base + lim == n) {                      // sentinel + trailing empty words
    for (int w = prev + 1; w <= nw; ++w) starts[w] = n;
  }
}

// ---------------- K2: 25 threads per word, LDS-resident table ----------------
// thread t -> word w = t/25, pair k = t%25. Store is ((float2*)out)[t]:
// perfectly coalesced (512B per wave). Persistent grid (512 blocks) so the
// 50KB table is staged only 512x (26MB total), not once per output tile.
__global__ __launch_bounds__(BLK, 8) void word_mean_v2(
    const int* __restrict__ char_ids, const float* __restrict__ table,
    const int* __restrict__ starts, float2* __restrict__ out2, int num_words) {
  __shared__ __align__(16) float tab[NB * EMB];   // 51200 B
  // cooperative float4 stage: 3200 float4
  for (int idx = threadIdx.x; idx < NB * EMB / 4; idx += BLK)
    ((float4*)tab)[idx] = ((const float4*)table)[idx];
  __syncthreads();

  const int total  = num_words * PAIRS;           // 40e6, fits int32
  const int stride = gridDim.x * BLK;
  for (int t = blockIdx.x * BLK + threadIdx.x; t < total; t += stride) {
    int w  = t / PAIRS;
    int k2 = (t - w * PAIRS) * 2;                 // float offset within row
    int s = starts[w];
    int e = starts[w + 1];
    float sx = 0.f, sy = 0.f;
    for (int i = s; i < e; ++i) {
      int c = char_ids[i];                        // broadcast across 25 lanes
      float2 v = *(const float2*)(tab + c * EMB + k2);  // 8B-aligned (200B rows)
      sx += v.x; sy += v.y;
    }
    int cnt = e - s;
    float inv = (cnt > 0) ? (1.0f / (float)cnt) : 0.0f;  // empty word -> zeros
    out2[t] = make_float2(sx * inv, sy * inv);
  }
}

// ---------------- fallback (ws too small): per-word binary search ------------
__device__ __forceinline__ int lb(const int* __restrict__ seg, int n, int w) {
  int lo = 0, hi = n;
  while (lo < hi) { int m = (lo + hi) >> 1; if (seg[m] < w) lo = m + 1; else hi = m; }
  return lo;
}
__global__ __launch_bounds__(256) void word_mean_bs_kernel(
    const int* __restrict__ char_ids, const int* __restrict__ seg,
    const float* __restrict__ table, float* __restrict__ out, int n, int num_words) {
  int w = blockIdx.x * blockDim.x + threadIdx.x;
  if (w >= num_words) return;
  int s = lb(seg, n, w), e = lb(seg, n, w + 1);
  float ax[PAIRS], ay[PAIRS];
#pragma unroll
  for (int k = 0; k < PAIRS; ++k) { ax[k] = 0.f; ay[k] = 0.f; }
  for (int i = s; i < e; ++i) {
    const float2* row = (const float2*)(table + char_ids[i] * EMB);
#pragma unroll
    for (int k = 0; k < PAIRS; ++k) { float2 v = row[k]; ax[k] += v.x; ay[k] += v.y; }
  }
  int cnt = e - s;
  float inv = (cnt > 0) ? (1.0f / (float)cnt) : 0.0f;
  float2* orow = (float2*)(out + (size_t)w * EMB);
#pragma unroll
  for (int k = 0; k < PAIRS; ++k) orow[k] = make_float2(ax[k] * inv, ay[k] * inv);
}

extern "C" void kernel_launch(void* const* d_in, const int* in_sizes, int n_in,
                              void* d_out, int out_size, void* d_ws, size_t ws_size,
                              hipStream_t stream) {
  const int*   char_ids = (const int*)d_in[0];
  const int*   seg      = (const int*)d_in[1];
  const float* table    = (const float*)d_in[3];
  float*       out      = (float*)d_out;

  const int n  = in_sizes[0];       // 8,000,000
  const int nw = out_size / EMB;    // 1,600,000

  if (ws_size >= (size_t)(nw + 1) * sizeof(int)) {
    int* starts = (int*)d_ws;
    int nchunk = (n + 3) / 4;
    seg_starts4<<<(nchunk + 255) / 256, 256, 0, stream>>>(seg, starts, n, nw);
    word_mean_v2<<<512, BLK, 0, stream>>>(char_ids, table, starts,
                                          (float2*)out, nw);
  } else {
    word_mean_bs_kernel<<<(nw + 255) / 256, 256, 0, stream>>>(
        char_ids, seg, table, out, n, nw);
  }
}

// Round 4
// 498.476 us; speedup vs baseline: 1.1317x; 1.0972x over previous
//
#include <hip/hip_runtime.h>

// Fused ragged gather + segment-mean (sorted segment_ids).
// d_in[0] char_ids i32[8e6], d_in[1] segment_ids i32[8e6] sorted,
// d_in[2] num_words i32[1] (host uses out_size/50), d_in[3] table f32[256*50].
// Out: f32[num_words, 50].

#define NB 256
#define EMB 50
#define PAIRS 25          // float2 per embedding row
#define BLK 1024
#define UNROLL 8          // char-batch: 8 independent global loads then 8 LDS gathers

// ---- K1: starts[w] = lower_bound(seg, w), w in [0, nw]; 4 chars/thread ----
__global__ __launch_bounds__(256) void seg_starts4(
    const int* __restrict__ seg, int* __restrict__ starts, int n, int nw) {
  int base = (blockIdx.x * blockDim.x + threadIdx.x) * 4;
  if (base >= n) return;
  int lim = n - base; if (lim > 4) lim = 4;
  int vals[4];
  if (lim == 4) {
    int4 v = *(const int4*)(seg + base);
    vals[0] = v.x; vals[1] = v.y; vals[2] = v.z; vals[3] = v.w;
  } else {
    for (int u = 0; u < lim; ++u) vals[u] = seg[base + u];
  }
  int prev = (base > 0) ? seg[base - 1] : -1;
  for (int u = 0; u < lim; ++u) {
    int cur = vals[u];
    for (int w = prev + 1; w <= cur; ++w) starts[w] = base + u;
    prev = cur;
  }
  if (base + lim == n) {                      // sentinel + trailing empty words
    for (int w = prev + 1; w <= nw; ++w) starts[w] = n;
  }
}

// ---- K2: 32 lanes per word (25 active), LDS table, 8-wide char batching ----
__global__ __launch_bounds__(BLK) void word_mean_v3(
    const int* __restrict__ char_ids, const float* __restrict__ table,
    const int* __restrict__ starts, float2* __restrict__ out2, int num_words) {
  __shared__ __align__(16) float tab[NB * EMB];   // 51200 B -> 2 blocks/CU (100% occ cap)
  for (int idx = threadIdx.x; idx < NB * EMB / 4; idx += BLK)
    ((float4*)tab)[idx] = ((const float4*)table)[idx];
  __syncthreads();

  const int k      = threadIdx.x & 31;        // lane within word-group
  const int g      = threadIdx.x >> 5;        // word slot in block (0..31)
  const bool active = (k < PAIRS);
  const int k2     = (active ? k : 0) * 2;    // float offset within row
  const int wstep  = gridDim.x * (BLK / 32);

  for (int w = blockIdx.x * (BLK / 32) + g; w < num_words; w += wstep) {
    int s = starts[w];
    int e = starts[w + 1];
    int cnt = e - s;
    if (!active) e = s;                       // idle lanes skip the char loop
    float sx = 0.f, sy = 0.f;

    for (int i = s; i < e; i += UNROLL) {
      int cs[UNROLL];
#pragma unroll
      for (int j = 0; j < UNROLL; ++j) {      // 8 independent global loads
        int idx = i + j;
        cs[j] = (idx < e) ? char_ids[idx] : -1;
      }
#pragma unroll
      for (int j = 0; j < UNROLL; ++j) {      // 8 independent LDS gathers
        if (cs[j] >= 0) {
          float2 v = *(const float2*)(tab + cs[j] * EMB + k2);  // 8B aligned
          sx += v.x; sy += v.y;
        }
      }
    }

    if (active) {
      float inv = (cnt > 0) ? (1.0f / (float)cnt) : 0.0f;  // empty word -> zeros
      out2[(size_t)w * PAIRS + k] = make_float2(sx * inv, sy * inv);
    }
  }
}

// ---- fallback (ws too small): per-word binary search ----
__device__ __forceinline__ int lb(const int* __restrict__ seg, int n, int w) {
  int lo = 0, hi = n;
  while (lo < hi) { int m = (lo + hi) >> 1; if (seg[m] < w) lo = m + 1; else hi = m; }
  return lo;
}
__global__ __launch_bounds__(256) void word_mean_bs_kernel(
    const int* __restrict__ char_ids, const int* __restrict__ seg,
    const float* __restrict__ table, float* __restrict__ out, int n, int num_words) {
  int w = blockIdx.x * blockDim.x + threadIdx.x;
  if (w >= num_words) return;
  int s = lb(seg, n, w), e = lb(seg, n, w + 1);
  float ax[PAIRS], ay[PAIRS];
#pragma unroll
  for (int p = 0; p < PAIRS; ++p) { ax[p] = 0.f; ay[p] = 0.f; }
  for (int i = s; i < e; ++i) {
    const float2* row = (const float2*)(table + char_ids[i] * EMB);
#pragma unroll
    for (int p = 0; p < PAIRS; ++p) { float2 v = row[p]; ax[p] += v.x; ay[p] += v.y; }
  }
  int cnt = e - s;
  float inv = (cnt > 0) ? (1.0f / (float)cnt) : 0.0f;
  float2* orow = (float2*)(out + (size_t)w * EMB);
#pragma unroll
  for (int p = 0; p < PAIRS; ++p) orow[p] = make_float2(ax[p] * inv, ay[p] * inv);
}

extern "C" void kernel_launch(void* const* d_in, const int* in_sizes, int n_in,
                              void* d_out, int out_size, void* d_ws, size_t ws_size,
                              hipStream_t stream) {
  const int*   char_ids = (const int*)d_in[0];
  const int*   seg      = (const int*)d_in[1];
  const float* table    = (const float*)d_in[3];
  float*       out      = (float*)d_out;

  const int n  = in_sizes[0];       // 8,000,000
  const int nw = out_size / EMB;    // 1,600,000

  if (ws_size >= (size_t)(nw + 1) * sizeof(int)) {
    int* starts = (int*)d_ws;
    int nchunk = (n + 3) / 4;
    seg_starts4<<<(nchunk + 255) / 256, 256, 0, stream>>>(seg, starts, n, nw);
    word_mean_v3<<<512, BLK, 0, stream>>>(char_ids, table, starts,
                                          (float2*)out, nw);
  } else {
    word_mean_bs_kernel<<<(nw + 255) / 256, 256, 0, stream>>>(
        char_ids, seg, table, out, n, nw);
  }
}